// Round 2
// baseline (943.756 us; speedup 1.0000x reference)
//
#include <hip/hip_runtime.h>
#include <cstdint>

#define ALPHA_F 0.1f
static const int NB    = 4;
static const int N_D   = 32768;   // 2^15
static const int N_E   = 65536;   // 2^16
static const int NEDGE = 262144;
static const int H     = 128;

// ---------------- CSR build ----------------

__global__ void count_kernel(const int* __restrict__ e2d, const int* __restrict__ d2e,
                             int* __restrict__ cnt_d, int* __restrict__ cnt_e, int E) {
  int k = blockIdx.x * blockDim.x + threadIdx.x;
  if (k >= E) return;
  atomicAdd(&cnt_d[e2d[E + k]], 1);   // d_dst of e2d
  atomicAdd(&cnt_e[d2e[E + k]], 1);   // e_dst of d2e
}

// exclusive scan of n ints (n multiple of 1024), writes off[0..n] and cursor[0..n-1]
__global__ void scan_kernel(const int* __restrict__ cnt, int* __restrict__ off,
                            int* __restrict__ cursor, int n) {
  __shared__ int partial[1024];
  int tid = threadIdx.x;
  int chunk = n >> 10;
  int base = tid * chunk;
  int sum = 0;
  for (int i = 0; i < chunk; ++i) sum += cnt[base + i];
  partial[tid] = sum;
  __syncthreads();
  for (int s = 1; s < 1024; s <<= 1) {
    int v = (tid >= s) ? partial[tid - s] : 0;
    __syncthreads();
    partial[tid] += v;
    __syncthreads();
  }
  int run = partial[tid] - sum;   // exclusive prefix
  for (int i = 0; i < chunk; ++i) {
    off[base + i] = run;
    cursor[base + i] = run;
    run += cnt[base + i];
  }
  if (tid == 1023) off[n] = run;
}

__global__ void fill_kernel(const int* __restrict__ e2d, const int* __restrict__ d2e,
                            int* __restrict__ cur_d, int* __restrict__ cur_e,
                            int* __restrict__ list_d, int* __restrict__ list_e, int E) {
  int k = blockIdx.x * blockDim.x + threadIdx.x;
  if (k >= E) return;
  int es = e2d[k], dd = e2d[E + k];
  int p1 = atomicAdd(&cur_d[dd], 1);
  list_d[p1] = es;                     // sources (e nodes) per d node
  int ds = d2e[k], ed = d2e[E + k];
  int p2 = atomicAdd(&cur_e[ed], 1);
  list_e[p2] = ds;                     // sources (d nodes) per e node
}

// ---------------- pt = clip(-tanh(llr/2)) ----------------
// one wave per (b,e) row; dot(hE_row, w_llr)
__global__ void pt_kernel(const float* __restrict__ hE, const float* __restrict__ w_llr,
                          float* __restrict__ pt, int nrows) {
  int wave = (blockIdx.x * blockDim.x + threadIdx.x) >> 6;
  int lane = threadIdx.x & 63;
  if (wave >= nrows) return;
  float2 v = reinterpret_cast<const float2*>(hE)[(size_t)wave * 64 + lane];
  float2 w = reinterpret_cast<const float2*>(w_llr)[lane];
  float s = v.x * w.x + v.y * w.y;
  #pragma unroll
  for (int off = 32; off > 0; off >>= 1) s += __shfl_down(s, off, 64);
  if (lane == 0) {
    float p = -tanhf(0.5f * s);
    pt[wave] = fminf(fmaxf(p, -0.999f), 0.999f);
  }
}

// ---------------- parity per (b,d) ----------------
__global__ void parity_kernel(const float* __restrict__ pt, const int* __restrict__ off_d,
                              const int* __restrict__ list_d, float* __restrict__ parity,
                              int total) {
  int idx = blockIdx.x * blockDim.x + threadIdx.x;
  if (idx >= total) return;
  int d = idx & (N_D - 1);
  int b = idx >> 15;
  const float* ptb = pt + (size_t)b * N_E;
  int s = off_d[d], t = off_d[d + 1];
  float lg = 0.0f;
  int neg = 0;
  for (int i = s; i < t; ++i) {
    float p = ptb[list_d[i]];
    lg += logf(fmaxf(fabsf(p), 1e-8f));
    neg ^= (p < 0.0f) ? 1 : 0;
  }
  float par = expf(fminf(lg, 20.0f));   // lg <= 0 always; exp in (0,1]
  parity[idx] = neg ? -par : par;
}

// ---------------- fused MLP: hD_new = hD + a*(relu([hD,par]@w1^T+b1)@w2^T+b2) ----------------
// block 512: c=tid&31 owns outputs 4c..4c+3, r=tid>>5 owns row r of 16-row tile.
__global__ void __launch_bounds__(512) mlp_kernel(
    const float* __restrict__ hD, const float* __restrict__ parity,
    const float* __restrict__ w1, const float* __restrict__ b1,
    const float* __restrict__ w2, const float* __restrict__ b2,
    float* __restrict__ outD, int ntiles) {
  extern __shared__ float lds[];
  float* w1t = lds;               // [129][128] transposed
  float* w2t = w1t + 129 * 128;   // [128][128] transposed
  float* b1s = w2t + 128 * 128;
  float* b2s = b1s + 128;
  float* xs  = b2s + 128;         // [16][129]
  float* h1s = xs + 16 * 129;     // [16][128]

  int tid = threadIdx.x;
  for (int idx = tid; idx < 128 * 129; idx += 512) {
    int i = idx / 129, j = idx - i * 129;   // coalesced read of w1[i][j]
    w1t[j * 128 + i] = w1[idx];
  }
  for (int idx = tid; idx < 128 * 128; idx += 512) {
    int i = idx >> 7, j = idx & 127;
    w2t[j * 128 + i] = w2[idx];
  }
  if (tid < 128) { b1s[tid] = b1[tid]; b2s[tid] = b2[tid]; }

  int c = tid & 31;
  int r = tid >> 5;
  int o = c * 4;

  for (int tile = blockIdx.x; tile < ntiles; tile += gridDim.x) {
    size_t rowbase = (size_t)tile * 16;
    __syncthreads();   // also covers initial weight staging
    for (int idx = tid; idx < 16 * 128; idx += 512) {
      int r2 = idx >> 7, j = idx & 127;
      xs[r2 * 129 + j] = hD[(rowbase + r2) * 128 + j];
    }
    if (tid < 16) xs[tid * 129 + 128] = parity[rowbase + tid];
    __syncthreads();

    float a0 = b1s[o], a1 = b1s[o + 1], a2 = b1s[o + 2], a3 = b1s[o + 3];
    const float* xr = xs + r * 129;
    #pragma unroll 4
    for (int j = 0; j < 129; ++j) {
      float xv = xr[j];
      float4 wv = *reinterpret_cast<const float4*>(&w1t[j * 128 + o]);
      a0 += wv.x * xv; a1 += wv.y * xv; a2 += wv.z * xv; a3 += wv.w * xv;
    }
    float4 h;
    h.x = fmaxf(a0, 0.f); h.y = fmaxf(a1, 0.f);
    h.z = fmaxf(a2, 0.f); h.w = fmaxf(a3, 0.f);
    *reinterpret_cast<float4*>(&h1s[r * 128 + o]) = h;
    __syncthreads();

    float c0 = b2s[o], c1 = b2s[o + 1], c2 = b2s[o + 2], c3 = b2s[o + 3];
    const float* hr = h1s + r * 128;
    #pragma unroll 4
    for (int j = 0; j < 128; ++j) {
      float hv = hr[j];
      float4 wv = *reinterpret_cast<const float4*>(&w2t[j * 128 + o]);
      c0 += wv.x * hv; c1 += wv.y * hv; c2 += wv.z * hv; c3 += wv.w * hv;
    }
    size_t rowoff = (rowbase + r) * 128 + o;
    float4 hd = *reinterpret_cast<const float4*>(&hD[rowoff]);
    float4 out;
    out.x = hd.x + ALPHA_F * c0; out.y = hd.y + ALPHA_F * c1;
    out.z = hd.z + ALPHA_F * c2; out.w = hd.w + ALPHA_F * c3;
    *reinterpret_cast<float4*>(&outD[rowoff]) = out;
  }
}

// ---------------- hD_sb = hD_new @ w_sb^T ----------------
__global__ void __launch_bounds__(512) sb_kernel(
    const float* __restrict__ hDn, const float* __restrict__ w_sb,
    float* __restrict__ hD_sb, int ntiles) {
  extern __shared__ float lds[];
  float* wst = lds;               // [128][128] transposed
  float* xs  = wst + 128 * 128;   // [16][128]
  int tid = threadIdx.x;
  for (int idx = tid; idx < 128 * 128; idx += 512) {
    int i = idx >> 7, j = idx & 127;
    wst[j * 128 + i] = w_sb[idx];
  }
  int c = tid & 31, r = tid >> 5, o = c * 4;
  for (int tile = blockIdx.x; tile < ntiles; tile += gridDim.x) {
    size_t rowbase = (size_t)tile * 16;
    __syncthreads();
    for (int idx = tid; idx < 16 * 128; idx += 512) {
      int r2 = idx >> 7, j = idx & 127;
      xs[idx] = hDn[(rowbase + r2) * 128 + j];
    }
    __syncthreads();
    float a0 = 0.f, a1 = 0.f, a2 = 0.f, a3 = 0.f;
    const float* xr = xs + r * 128;
    #pragma unroll 4
    for (int j = 0; j < 128; ++j) {
      float xv = xr[j];
      float4 wv = *reinterpret_cast<const float4*>(&wst[j * 128 + o]);
      a0 += wv.x * xv; a1 += wv.y * xv; a2 += wv.z * xv; a3 += wv.w * xv;
    }
    size_t rowoff = (rowbase + r) * 128 + o;
    float4 out = make_float4(a0, a1, a2, a3);
    *reinterpret_cast<float4*>(&hD_sb[rowoff]) = out;
  }
}

// ---------------- hE_new = hE + a * (sum gathered hD_sb rows)/count ----------------
// one wave per (b,e) row
__global__ void agg_kernel(const float* __restrict__ hE, const float* __restrict__ hD_sb,
                           const int* __restrict__ off_e, const int* __restrict__ list_e,
                           float* __restrict__ outE, int nrows) {
  int wave = (blockIdx.x * blockDim.x + threadIdx.x) >> 6;
  int lane = threadIdx.x & 63;
  if (wave >= nrows) return;
  int e = wave & (N_E - 1);
  int b = wave >> 16;
  int s = off_e[e], t = off_e[e + 1];
  float accx = 0.f, accy = 0.f;
  const float2* sb_b = reinterpret_cast<const float2*>(hD_sb) + (size_t)b * N_D * 64;
  for (int i = s; i < t; ++i) {
    int d = list_e[i];
    float2 v = sb_b[(size_t)d * 64 + lane];
    accx += v.x; accy += v.y;
  }
  float cnt = (float)((t - s) > 0 ? (t - s) : 1);
  float2 he = reinterpret_cast<const float2*>(hE)[(size_t)wave * 64 + lane];
  float2 out;
  out.x = he.x + ALPHA_F * (accx / cnt);
  out.y = he.y + ALPHA_F * (accy / cnt);
  reinterpret_cast<float2*>(outE)[(size_t)wave * 64 + lane] = out;
}

// ---------------- launch ----------------

extern "C" void kernel_launch(void* const* d_in, const int* in_sizes, int n_in,
                              void* d_out, int out_size, void* d_ws, size_t ws_size,
                              hipStream_t stream) {
  const float* hD    = (const float*)d_in[0];
  const float* hE    = (const float*)d_in[1];
  const int*   e2d   = (const int*)d_in[2];
  const int*   d2e   = (const int*)d_in[3];
  const float* w_llr = (const float*)d_in[4];
  const float* w1    = (const float*)d_in[5];
  const float* b1    = (const float*)d_in[6];
  const float* w2    = (const float*)d_in[7];
  const float* b2    = (const float*)d_in[8];
  const float* w_sb  = (const float*)d_in[9];

  float* outD = (float*)d_out;
  float* outE = outD + (size_t)NB * N_D * H;

  float* pt     = (float*)d_ws;
  float* parity = pt + (size_t)NB * N_E;
  float* hD_sb  = parity + (size_t)NB * N_D;
  int* cnt_d  = (int*)(hD_sb + (size_t)NB * N_D * H);
  int* off_d  = cnt_d + N_D;
  int* cur_d  = off_d + N_D + 1;
  int* cnt_e  = cur_d + N_D;
  int* off_e  = cnt_e + N_E;
  int* cur_e  = off_e + N_E + 1;
  int* list_d = cur_e + N_E;
  int* list_e = list_d + NEDGE;

  hipMemsetAsync(cnt_d, 0, N_D * sizeof(int), stream);
  hipMemsetAsync(cnt_e, 0, N_E * sizeof(int), stream);

  count_kernel<<<NEDGE / 256, 256, 0, stream>>>(e2d, d2e, cnt_d, cnt_e, NEDGE);
  scan_kernel<<<1, 1024, 0, stream>>>(cnt_d, off_d, cur_d, N_D);
  scan_kernel<<<1, 1024, 0, stream>>>(cnt_e, off_e, cur_e, N_E);
  fill_kernel<<<NEDGE / 256, 256, 0, stream>>>(e2d, d2e, cur_d, cur_e, list_d, list_e, NEDGE);

  pt_kernel<<<(NB * N_E) / 4, 256, 0, stream>>>(hE, w_llr, pt, NB * N_E);
  parity_kernel<<<(NB * N_D) / 256, 256, 0, stream>>>(pt, off_d, list_d, parity, NB * N_D);

  size_t mlp_lds = (size_t)(129 * 128 + 128 * 128 + 128 + 128 + 16 * 129 + 16 * 128) * 4;
  hipFuncSetAttribute((const void*)mlp_kernel, hipFuncAttributeMaxDynamicSharedMemorySize, (int)mlp_lds);
  mlp_kernel<<<256, 512, mlp_lds, stream>>>(hD, parity, w1, b1, w2, b2, outD, (NB * N_D) / 16);

  size_t sb_lds = (size_t)(128 * 128 + 16 * 128) * 4;
  hipFuncSetAttribute((const void*)sb_kernel, hipFuncAttributeMaxDynamicSharedMemorySize, (int)sb_lds);
  sb_kernel<<<512, 512, sb_lds, stream>>>(outD, w_sb, hD_sb, (NB * N_D) / 16);

  agg_kernel<<<(NB * N_E) / 4, 256, 0, stream>>>(hE, hD_sb, off_e, list_e, outE, NB * N_E);
}

// Round 4
// 576.830 us; speedup vs baseline: 1.6361x; 1.6361x over previous
//
#include <hip/hip_runtime.h>
#include <cstdint>

#define ALPHA_F 0.1f
static const int NB    = 4;
static const int N_D   = 32768;   // 2^15
static const int N_E   = 65536;   // 2^16
static const int NEDGE = 262144;
static const int H     = 128;

typedef __attribute__((ext_vector_type(8))) short short8;
typedef __attribute__((ext_vector_type(4))) float f32x4;

__device__ __forceinline__ unsigned short f2bf(float x) {
  union { float f; unsigned u; } v; v.f = x;
  unsigned u = v.u + (0x7FFFu + ((v.u >> 16) & 1u));   // RNE
  return (unsigned short)(u >> 16);
}
__device__ __forceinline__ float bf2f(unsigned short h) {
  union { unsigned u; float f; } v; v.u = ((unsigned)h) << 16;
  return v.f;
}
// byte offset of element k-byte `kbyte` in row `row` of a [R][128]-bf16 LDS tile,
// XOR-swizzled so 16 lanes reading the same k of rows 0..15 spread across 8 bank-quads
__device__ __forceinline__ int swzb(int row, int kbyte) {
  return (row * 256 + kbyte) ^ ((row & 7) << 4);
}

// ---------------- CSR build ----------------

__global__ void count_kernel(const int* __restrict__ e2d, const int* __restrict__ d2e,
                             int* __restrict__ cnt_d, int* __restrict__ cnt_e, int E) {
  int k = blockIdx.x * blockDim.x + threadIdx.x;
  if (k >= E) return;
  atomicAdd(&cnt_d[e2d[E + k]], 1);
  atomicAdd(&cnt_e[d2e[E + k]], 1);
}

__global__ void scan_kernel(const int* __restrict__ cnt, int* __restrict__ off,
                            int* __restrict__ cursor, int n) {
  __shared__ int partial[1024];
  int tid = threadIdx.x;
  int chunk = n >> 10;
  int base = tid * chunk;
  int sum = 0;
  for (int i = 0; i < chunk; ++i) sum += cnt[base + i];
  partial[tid] = sum;
  __syncthreads();
  for (int s = 1; s < 1024; s <<= 1) {
    int v = (tid >= s) ? partial[tid - s] : 0;
    __syncthreads();
    partial[tid] += v;
    __syncthreads();
  }
  int run = partial[tid] - sum;
  for (int i = 0; i < chunk; ++i) {
    off[base + i] = run;
    cursor[base + i] = run;
    run += cnt[base + i];
  }
  if (tid == 1023) off[n] = run;
}

__global__ void fill_kernel(const int* __restrict__ e2d, const int* __restrict__ d2e,
                            int* __restrict__ cur_d, int* __restrict__ cur_e,
                            int* __restrict__ list_d, int* __restrict__ list_e, int E) {
  int k = blockIdx.x * blockDim.x + threadIdx.x;
  if (k >= E) return;
  int es = e2d[k], dd = e2d[E + k];
  int p1 = atomicAdd(&cur_d[dd], 1);
  list_d[p1] = es;
  int ds = d2e[k], ed = d2e[E + k];
  int p2 = atomicAdd(&cur_e[ed], 1);
  list_e[p2] = ds;
}

// ---------------- pt = clip(-tanh(llr/2)) ----------------
__global__ void pt_kernel(const float* __restrict__ hE, const float* __restrict__ w_llr,
                          float* __restrict__ pt, int nrows) {
  int wave = (blockIdx.x * blockDim.x + threadIdx.x) >> 6;
  int lane = threadIdx.x & 63;
  if (wave >= nrows) return;
  float2 v = reinterpret_cast<const float2*>(hE)[(size_t)wave * 64 + lane];
  float2 w = reinterpret_cast<const float2*>(w_llr)[lane];
  float s = v.x * w.x + v.y * w.y;
  #pragma unroll
  for (int off = 32; off > 0; off >>= 1) s += __shfl_down(s, off, 64);
  if (lane == 0) {
    float p = -tanhf(0.5f * s);
    pt[wave] = fminf(fmaxf(p, -0.999f), 0.999f);
  }
}

// ---------------- parity per (b,d) ----------------
__global__ void parity_kernel(const float* __restrict__ pt, const int* __restrict__ off_d,
                              const int* __restrict__ list_d, float* __restrict__ parity,
                              int total) {
  int idx = blockIdx.x * blockDim.x + threadIdx.x;
  if (idx >= total) return;
  int d = idx & (N_D - 1);
  int b = idx >> 15;
  const float* ptb = pt + (size_t)b * N_E;
  int s = off_d[d], t = off_d[d + 1];
  float lg = 0.0f;
  int neg = 0;
  for (int i = s; i < t; ++i) {
    float p = ptb[list_d[i]];
    lg += logf(fmaxf(fabsf(p), 1e-8f));
    neg ^= (p < 0.0f) ? 1 : 0;
  }
  float par = expf(fminf(lg, 20.0f));
  parity[idx] = neg ? -par : par;
}

// ---------------- weight pre-pack to bf16 ----------------
__global__ void wsplit_kernel(const float* __restrict__ w1, const float* __restrict__ w2,
                              const float* __restrict__ wsb,
                              unsigned short* __restrict__ w1b, float* __restrict__ w1last,
                              unsigned short* __restrict__ w2b, unsigned short* __restrict__ wsbb) {
  int idx = blockIdx.x * blockDim.x + threadIdx.x;
  if (idx >= 128 * 128) return;
  int n = idx >> 7, k = idx & 127;
  w1b[idx]  = f2bf(w1[n * 129 + k]);
  w2b[idx]  = f2bf(w2[idx]);
  wsbb[idx] = f2bf(wsb[idx]);
  if (k == 0) w1last[n] = w1[n * 129 + 128];
}

// stage a 128x128 bf16 weight matrix (row-major, 16B chunks) into swizzled LDS
__device__ __forceinline__ void stage_w(const uint4* __restrict__ src,
                                        unsigned short* wb, int tid) {
  #pragma unroll
  for (int r = 0; r < 8; ++r) {
    int i = tid + r * 256;            // 2048 chunks of 16B
    int n = i >> 4, kc = (i & 15) << 4;
    *(uint4*)((char*)wb + ((n * 256 + kc) ^ ((n & 7) << 4))) = src[i];
  }
}

// one layer: acc[ct] += sum_k (xhi+xlo)[arow][k] * w[ct*16+lrow][k], K=128
__device__ __forceinline__ void gemm64(f32x4* acc, const char* xhiB, const char* xloB,
                                       const char* wbB, int arow, int lrow, int lkg) {
  int kb0 = lkg << 4;
  #pragma unroll
  for (int ks = 0; ks < 4; ++ks) {
    int kb = (ks << 6) + kb0;
    short8 ahi = *(const short8*)(xhiB + swzb(arow, kb));
    short8 alo = *(const short8*)(xloB + swzb(arow, kb));
    #pragma unroll
    for (int ct = 0; ct < 8; ++ct) {
      short8 b = *(const short8*)(wbB + swzb(ct * 16 + lrow, kb));
      acc[ct] = __builtin_amdgcn_mfma_f32_16x16x32_bf16(ahi, b, acc[ct], 0, 0, 0);
      acc[ct] = __builtin_amdgcn_mfma_f32_16x16x32_bf16(alo, b, acc[ct], 0, 0, 0);
    }
  }
}

// ---------------- fused: hD_new = hD + a*MLP([hD,par]); hD_sb = hD_new @ w_sb^T ----------------
// 256 threads = 4 waves; each wave owns 16 rows x 128 cols; block tile = 64 rows.
__global__ void __launch_bounds__(256) fused_kernel(
    const float* __restrict__ hD, const float* __restrict__ parity,
    const unsigned short* __restrict__ w1b, const float* __restrict__ w1last,
    const float* __restrict__ b1, const unsigned short* __restrict__ w2b,
    const float* __restrict__ b2, const unsigned short* __restrict__ wsbb,
    float* __restrict__ outD, float* __restrict__ hD_sb) {
  extern __shared__ char lds[];
  unsigned short* xhi = (unsigned short*)lds;          // [64][128] bf16, swizzled
  unsigned short* xlo = xhi + 64 * 128;
  unsigned short* wb  = xlo + 64 * 128;                // [128][128] bf16, swizzled
  float* pbuf  = (float*)(wb + 128 * 128);             // [64]
  float* wlast = pbuf + 64;                            // [128]
  float* b1s   = wlast + 128;
  float* b2s   = b1s + 128;

  int tid  = threadIdx.x;
  int lane = tid & 63, wv = tid >> 6;
  int lrow = lane & 15, lkg = lane >> 4;
  int wrow = wv << 4;
  size_t rowbase = (size_t)blockIdx.x << 6;

  // stage x = hD tile (split hi/lo bf16)
  const float4* hD4 = (const float4*)(hD + (rowbase << 7));
  #pragma unroll
  for (int it = 0; it < 8; ++it) {
    int i = tid + it * 256;                    // 2048 float4 = 64 rows x 32
    float4 v = hD4[i];
    int row = i >> 5, kb = (i & 31) << 3;      // byte offset within row (bf16*2 per elem)
    unsigned short h0 = f2bf(v.x), h1 = f2bf(v.y), h2 = f2bf(v.z), h3 = f2bf(v.w);
    unsigned short l0 = f2bf(v.x - bf2f(h0)), l1 = f2bf(v.y - bf2f(h1));
    unsigned short l2 = f2bf(v.z - bf2f(h2)), l3 = f2bf(v.w - bf2f(h3));
    *(unsigned*)((char*)xhi + swzb(row, kb))     = h0 | ((unsigned)h1 << 16);
    *(unsigned*)((char*)xhi + swzb(row, kb + 4)) = h2 | ((unsigned)h3 << 16);
    *(unsigned*)((char*)xlo + swzb(row, kb))     = l0 | ((unsigned)l1 << 16);
    *(unsigned*)((char*)xlo + swzb(row, kb + 4)) = l2 | ((unsigned)l3 << 16);
  }
  stage_w((const uint4*)w1b, wb, tid);
  if (tid < 64) pbuf[tid] = parity[rowbase + tid];
  if (tid < 128) { wlast[tid] = w1last[tid]; b1s[tid] = b1[tid]; b2s[tid] = b2[tid]; }
  __syncthreads();

  // ---- layer 1 ----
  f32x4 acc[8];
  #pragma unroll
  for (int ct = 0; ct < 8; ++ct) acc[ct] = (f32x4){0.f, 0.f, 0.f, 0.f};
  gemm64(acc, (char*)xhi, (char*)xlo, (char*)wb, wrow + lrow, lrow, lkg);
  __syncthreads();

  stage_w((const uint4*)w2b, wb, tid);   // overwrite weights for layer 2
  #pragma unroll
  for (int ct = 0; ct < 8; ++ct) {
    int col = ct * 16 + lrow;
    float wl = wlast[col], bb = b1s[col];
    #pragma unroll
    for (int q = 0; q < 4; ++q) {
      int row = wrow + (lkg << 2) + q;
      float y = acc[ct][q] + bb + pbuf[row] * wl;   // parity column (k=128), exact f32
      y = fmaxf(y, 0.0f);
      unsigned short h = f2bf(y);
      *(unsigned short*)((char*)xhi + swzb(row, col << 1)) = h;
      *(unsigned short*)((char*)xlo + swzb(row, col << 1)) = f2bf(y - bf2f(h));
    }
  }
  __syncthreads();

  // ---- layer 2 ----
  #pragma unroll
  for (int ct = 0; ct < 8; ++ct) acc[ct] = (f32x4){0.f, 0.f, 0.f, 0.f};
  gemm64(acc, (char*)xhi, (char*)xlo, (char*)wb, wrow + lrow, lrow, lkg);
  __syncthreads();

  stage_w((const uint4*)wsbb, wb, tid);  // weights for layer 3
  #pragma unroll
  for (int ct = 0; ct < 8; ++ct) {
    int col = ct * 16 + lrow;
    float bb = b2s[col];
    #pragma unroll
    for (int q = 0; q < 4; ++q) {
      int row = wrow + (lkg << 2) + q;
      size_t g = ((rowbase + row) << 7) + col;
      float hn = hD[g] + ALPHA_F * (acc[ct][q] + bb);
      outD[g] = hn;
      unsigned short h = f2bf(hn);
      *(unsigned short*)((char*)xhi + swzb(row, col << 1)) = h;
      *(unsigned short*)((char*)xlo + swzb(row, col << 1)) = f2bf(hn - bf2f(h));
    }
  }
  __syncthreads();

  // ---- layer 3 (hD_sb) ----
  #pragma unroll
  for (int ct = 0; ct < 8; ++ct) acc[ct] = (f32x4){0.f, 0.f, 0.f, 0.f};
  gemm64(acc, (char*)xhi, (char*)xlo, (char*)wb, wrow + lrow, lrow, lkg);
  #pragma unroll
  for (int ct = 0; ct < 8; ++ct) {
    int col = ct * 16 + lrow;
    #pragma unroll
    for (int q = 0; q < 4; ++q) {
      int row = wrow + (lkg << 2) + q;
      hD_sb[((rowbase + row) << 7) + col] = acc[ct][q];
    }
  }
}

// ---------------- hE_new = hE + a * (sum gathered hD_sb rows)/count ----------------
__global__ void agg_kernel(const float* __restrict__ hE, const float* __restrict__ hD_sb,
                           const int* __restrict__ off_e, const int* __restrict__ list_e,
                           float* __restrict__ outE, int nrows) {
  int wave = (blockIdx.x * blockDim.x + threadIdx.x) >> 6;
  int lane = threadIdx.x & 63;
  if (wave >= nrows) return;
  int e = wave & (N_E - 1);
  int b = wave >> 16;
  int s = off_e[e], t = off_e[e + 1];
  float accx = 0.f, accy = 0.f;
  const float2* sb_b = reinterpret_cast<const float2*>(hD_sb) + (size_t)b * N_D * 64;
  for (int i = s; i < t; ++i) {
    int d = list_e[i];
    float2 v = sb_b[(size_t)d * 64 + lane];
    accx += v.x; accy += v.y;
  }
  float cnt = (float)((t - s) > 0 ? (t - s) : 1);
  float2 he = reinterpret_cast<const float2*>(hE)[(size_t)wave * 64 + lane];
  float2 out;
  out.x = he.x + ALPHA_F * (accx / cnt);
  out.y = he.y + ALPHA_F * (accy / cnt);
  reinterpret_cast<float2*>(outE)[(size_t)wave * 64 + lane] = out;
}

// ---------------- launch ----------------

extern "C" void kernel_launch(void* const* d_in, const int* in_sizes, int n_in,
                              void* d_out, int out_size, void* d_ws, size_t ws_size,
                              hipStream_t stream) {
  const float* hD    = (const float*)d_in[0];
  const float* hE    = (const float*)d_in[1];
  const int*   e2d   = (const int*)d_in[2];
  const int*   d2e   = (const int*)d_in[3];
  const float* w_llr = (const float*)d_in[4];
  const float* w1    = (const float*)d_in[5];
  const float* b1    = (const float*)d_in[6];
  const float* w2    = (const float*)d_in[7];
  const float* b2    = (const float*)d_in[8];
  const float* w_sb  = (const float*)d_in[9];

  float* outD = (float*)d_out;
  float* outE = outD + (size_t)NB * N_D * H;

  float* pt     = (float*)d_ws;
  float* parity = pt + (size_t)NB * N_E;
  float* hD_sb  = parity + (size_t)NB * N_D;
  int* cnt_d  = (int*)(hD_sb + (size_t)NB * N_D * H);
  int* off_d  = cnt_d + N_D;
  int* cur_d  = off_d + N_D + 1;
  int* cnt_e  = cur_d + N_D;
  int* off_e  = cnt_e + N_E;
  int* cur_e  = off_e + N_E + 1;
  int* list_d = cur_e + N_E;
  int* list_e = list_d + NEDGE;
  uintptr_t wp = (uintptr_t)(list_e + NEDGE);
  wp = (wp + 15) & ~(uintptr_t)15;
  unsigned short* w1b  = (unsigned short*)wp;            // 128*128 bf16
  unsigned short* w2b  = w1b + 128 * 128;
  unsigned short* wsbb = w2b + 128 * 128;
  float* w1last = (float*)(wsbb + 128 * 128);            // 128 f32

  hipMemsetAsync(cnt_d, 0, N_D * sizeof(int), stream);
  hipMemsetAsync(cnt_e, 0, N_E * sizeof(int), stream);

  count_kernel<<<NEDGE / 256, 256, 0, stream>>>(e2d, d2e, cnt_d, cnt_e, NEDGE);
  scan_kernel<<<1, 1024, 0, stream>>>(cnt_d, off_d, cur_d, N_D);
  scan_kernel<<<1, 1024, 0, stream>>>(cnt_e, off_e, cur_e, N_E);
  fill_kernel<<<NEDGE / 256, 256, 0, stream>>>(e2d, d2e, cur_d, cur_e, list_d, list_e, NEDGE);

  wsplit_kernel<<<64, 256, 0, stream>>>(w1, w2, w_sb, w1b, w1last, w2b, wsbb);

  pt_kernel<<<(NB * N_E) / 4, 256, 0, stream>>>(hE, w_llr, pt, NB * N_E);
  parity_kernel<<<(NB * N_D) / 256, 256, 0, stream>>>(pt, off_d, list_d, parity, NB * N_D);

  size_t fused_lds = (size_t)(64 * 128 * 2 * 2 + 128 * 128 * 2 + (64 + 128 + 128 + 128) * 4);
  hipFuncSetAttribute((const void*)fused_kernel, hipFuncAttributeMaxDynamicSharedMemorySize,
                      (int)fused_lds);
  fused_kernel<<<(NB * N_D) / 64, 256, fused_lds, stream>>>(
      hD, parity, w1b, w1last, b1, w2b, b2, wsbb, outD, hD_sb);

  agg_kernel<<<(NB * N_E) / 4, 256, 0, stream>>>(hE, hD_sb, off_e, list_e, outE, NB * N_E);
}

// Round 5
// 340.531 us; speedup vs baseline: 2.7714x; 1.6939x over previous
//
#include <hip/hip_runtime.h>
#include <cstdint>

#define ALPHA_F 0.1f
static const int NB    = 4;
static const int N_D   = 32768;   // 2^15
static const int N_E   = 65536;   // 2^16
static const int NEDGE = 262144;
static const int H     = 128;

typedef __attribute__((ext_vector_type(8))) short short8;
typedef __attribute__((ext_vector_type(4))) float f32x4;

__device__ __forceinline__ unsigned short f2bf(float x) {
  union { float f; unsigned u; } v; v.f = x;
  unsigned u = v.u + (0x7FFFu + ((v.u >> 16) & 1u));   // RNE
  return (unsigned short)(u >> 16);
}
__device__ __forceinline__ float bf2f(unsigned short h) {
  union { unsigned u; float f; } v; v.u = ((unsigned)h) << 16;
  return v.f;
}
// byte offset of element k-byte `kbyte` in row `row` of a [R][128]-bf16 LDS tile,
// XOR-swizzled so 16 lanes reading the same k of rows 0..15 spread across 8 bank-quads
__device__ __forceinline__ int swzb(int row, int kbyte) {
  return (row * 256 + kbyte) ^ ((row & 7) << 4);
}

// ---------------- CSR build ----------------

__global__ void count_kernel(const int* __restrict__ e2d, const int* __restrict__ d2e,
                             int* __restrict__ cnt_d, int* __restrict__ cnt_e, int E) {
  int k = blockIdx.x * blockDim.x + threadIdx.x;
  if (k >= E) return;
  atomicAdd(&cnt_d[e2d[E + k]], 1);
  atomicAdd(&cnt_e[d2e[E + k]], 1);
}

// exclusive scan of n ints, 1 block of 1024, CHUNK contiguous elems per thread
template <int CHUNK>
__global__ void scan_kernel(const int* __restrict__ cnt, int* __restrict__ off,
                            int* __restrict__ cursor, int n) {
  __shared__ int partial[1024];
  int tid = threadIdx.x;
  int base = tid * CHUNK;
  int4 vals[CHUNK / 4];
  const int4* c4 = (const int4*)(cnt + base);
  int sum = 0;
  #pragma unroll
  for (int i = 0; i < CHUNK / 4; ++i) {
    vals[i] = c4[i];
    sum += vals[i].x + vals[i].y + vals[i].z + vals[i].w;
  }
  partial[tid] = sum;
  __syncthreads();
  for (int s = 1; s < 1024; s <<= 1) {
    int v = (tid >= s) ? partial[tid - s] : 0;
    __syncthreads();
    partial[tid] += v;
    __syncthreads();
  }
  int run = partial[tid] - sum;
  int4* o4 = (int4*)(off + base);
  int4* cu4 = (int4*)(cursor + base);
  #pragma unroll
  for (int i = 0; i < CHUNK / 4; ++i) {
    int4 o;
    o.x = run; run += vals[i].x;
    o.y = run; run += vals[i].y;
    o.z = run; run += vals[i].z;
    o.w = run; run += vals[i].w;
    o4[i] = o;
    cu4[i] = o;
  }
  if (tid == 1023) off[n] = run;
}

__global__ void fill_kernel(const int* __restrict__ e2d, const int* __restrict__ d2e,
                            int* __restrict__ cur_d, int* __restrict__ cur_e,
                            int* __restrict__ list_d, int* __restrict__ list_e, int E) {
  int k = blockIdx.x * blockDim.x + threadIdx.x;
  if (k >= E) return;
  int es = e2d[k], dd = e2d[E + k];
  int p1 = atomicAdd(&cur_d[dd], 1);
  list_d[p1] = es;
  int ds = d2e[k], ed = d2e[E + k];
  int p2 = atomicAdd(&cur_e[ed], 1);
  list_e[p2] = ds;
}

// ---------------- pt = clip(-tanh(llr/2)) ----------------
__global__ void pt_kernel(const float* __restrict__ hE, const float* __restrict__ w_llr,
                          float* __restrict__ pt, int nrows) {
  int wave = (blockIdx.x * blockDim.x + threadIdx.x) >> 6;
  int lane = threadIdx.x & 63;
  if (wave >= nrows) return;
  float2 v = reinterpret_cast<const float2*>(hE)[(size_t)wave * 64 + lane];
  float2 w = reinterpret_cast<const float2*>(w_llr)[lane];
  float s = v.x * w.x + v.y * w.y;
  #pragma unroll
  for (int off = 32; off > 0; off >>= 1) s += __shfl_down(s, off, 64);
  if (lane == 0) {
    float p = -tanhf(0.5f * s);
    pt[wave] = fminf(fmaxf(p, -0.999f), 0.999f);
  }
}

// ---------------- parity per (b,d) ----------------
__global__ void parity_kernel(const float* __restrict__ pt, const int* __restrict__ off_d,
                              const int* __restrict__ list_d, float* __restrict__ parity,
                              int total) {
  int idx = blockIdx.x * blockDim.x + threadIdx.x;
  if (idx >= total) return;
  int d = idx & (N_D - 1);
  int b = idx >> 15;
  const float* ptb = pt + (size_t)b * N_E;
  int s = off_d[d], t = off_d[d + 1];
  float lg = 0.0f;
  int neg = 0;
  for (int i = s; i < t; ++i) {
    float p = ptb[list_d[i]];
    lg += logf(fmaxf(fabsf(p), 1e-8f));
    neg ^= (p < 0.0f) ? 1 : 0;
  }
  float par = expf(fminf(lg, 20.0f));
  parity[idx] = neg ? -par : par;
}

// ---------------- weight pre-pack to bf16 ----------------
__global__ void wsplit_kernel(const float* __restrict__ w1, const float* __restrict__ w2,
                              const float* __restrict__ wsb,
                              unsigned short* __restrict__ w1b, float* __restrict__ w1last,
                              unsigned short* __restrict__ w2b, unsigned short* __restrict__ wsbb) {
  int idx = blockIdx.x * blockDim.x + threadIdx.x;
  if (idx >= 128 * 128) return;
  int n = idx >> 7, k = idx & 127;
  w1b[idx]  = f2bf(w1[n * 129 + k]);
  w2b[idx]  = f2bf(w2[idx]);
  wsbb[idx] = f2bf(wsb[idx]);
  if (k == 0) w1last[n] = w1[n * 129 + 128];
}

// stage a 128x128 bf16 weight matrix (row-major, 16B chunks) into swizzled LDS
__device__ __forceinline__ void stage_w(const uint4* __restrict__ src,
                                        unsigned short* wb, int tid) {
  #pragma unroll
  for (int r = 0; r < 8; ++r) {
    int i = tid + r * 256;            // 2048 chunks of 16B
    int n = i >> 4, kc = (i & 15) << 4;
    *(uint4*)((char*)wb + ((n * 256 + kc) ^ ((n & 7) << 4))) = src[i];
  }
}

// one layer: acc[ct] += sum_k (xhi+xlo)[arow][k] * w[ct*16+lrow][k], K=128
__device__ __forceinline__ void gemm64(f32x4* acc, const char* xhiB, const char* xloB,
                                       const char* wbB, int arow, int lrow, int lkg) {
  int kb0 = lkg << 4;
  #pragma unroll
  for (int ks = 0; ks < 4; ++ks) {
    int kb = (ks << 6) + kb0;
    short8 ahi = *(const short8*)(xhiB + swzb(arow, kb));
    short8 alo = *(const short8*)(xloB + swzb(arow, kb));
    #pragma unroll
    for (int ct = 0; ct < 8; ++ct) {
      short8 b = *(const short8*)(wbB + swzb(ct * 16 + lrow, kb));
      acc[ct] = __builtin_amdgcn_mfma_f32_16x16x32_bf16(ahi, b, acc[ct], 0, 0, 0);
      acc[ct] = __builtin_amdgcn_mfma_f32_16x16x32_bf16(alo, b, acc[ct], 0, 0, 0);
    }
  }
}

// ---------------- fused: hD_new = hD + a*MLP([hD,par]); hD_sb = hD_new @ w_sb^T ----------------
// hD_sb written in [d][b][128] layout for the aggregation gather.
// 256 threads = 4 waves; each wave owns 16 rows x 128 cols; block tile = 64 rows.
__global__ void __launch_bounds__(256) fused_kernel(
    const float* __restrict__ hD, const float* __restrict__ parity,
    const unsigned short* __restrict__ w1b, const float* __restrict__ w1last,
    const float* __restrict__ b1, const unsigned short* __restrict__ w2b,
    const float* __restrict__ b2, const unsigned short* __restrict__ wsbb,
    float* __restrict__ outD, float* __restrict__ hD_sb) {
  extern __shared__ char lds[];
  unsigned short* xhi = (unsigned short*)lds;          // [64][128] bf16, swizzled
  unsigned short* xlo = xhi + 64 * 128;
  unsigned short* wb  = xlo + 64 * 128;                // [128][128] bf16, swizzled
  float* pbuf  = (float*)(wb + 128 * 128);             // [64]
  float* wlast = pbuf + 64;                            // [128]
  float* b1s   = wlast + 128;
  float* b2s   = b1s + 128;

  int tid  = threadIdx.x;
  int lane = tid & 63, wv = tid >> 6;
  int lrow = lane & 15, lkg = lane >> 4;
  int wrow = wv << 4;
  size_t rowbase = (size_t)blockIdx.x << 6;

  // stage x = hD tile (split hi/lo bf16)
  const float4* hD4 = (const float4*)(hD + (rowbase << 7));
  #pragma unroll
  for (int it = 0; it < 8; ++it) {
    int i = tid + it * 256;                    // 2048 float4 = 64 rows x 32
    float4 v = hD4[i];
    int row = i >> 5, kb = (i & 31) << 3;      // byte offset within row (bf16*2 per elem)
    unsigned short h0 = f2bf(v.x), h1 = f2bf(v.y), h2 = f2bf(v.z), h3 = f2bf(v.w);
    unsigned short l0 = f2bf(v.x - bf2f(h0)), l1 = f2bf(v.y - bf2f(h1));
    unsigned short l2 = f2bf(v.z - bf2f(h2)), l3 = f2bf(v.w - bf2f(h3));
    *(unsigned*)((char*)xhi + swzb(row, kb))     = h0 | ((unsigned)h1 << 16);
    *(unsigned*)((char*)xhi + swzb(row, kb + 4)) = h2 | ((unsigned)h3 << 16);
    *(unsigned*)((char*)xlo + swzb(row, kb))     = l0 | ((unsigned)l1 << 16);
    *(unsigned*)((char*)xlo + swzb(row, kb + 4)) = l2 | ((unsigned)l3 << 16);
  }
  stage_w((const uint4*)w1b, wb, tid);
  if (tid < 64) pbuf[tid] = parity[rowbase + tid];
  if (tid < 128) { wlast[tid] = w1last[tid]; b1s[tid] = b1[tid]; b2s[tid] = b2[tid]; }
  __syncthreads();

  // ---- layer 1 ----
  f32x4 acc[8];
  #pragma unroll
  for (int ct = 0; ct < 8; ++ct) acc[ct] = (f32x4){0.f, 0.f, 0.f, 0.f};
  gemm64(acc, (char*)xhi, (char*)xlo, (char*)wb, wrow + lrow, lrow, lkg);
  __syncthreads();

  stage_w((const uint4*)w2b, wb, tid);   // overwrite weights for layer 2
  #pragma unroll
  for (int ct = 0; ct < 8; ++ct) {
    int col = ct * 16 + lrow;
    float wl = wlast[col], bb = b1s[col];
    #pragma unroll
    for (int q = 0; q < 4; ++q) {
      int row = wrow + (lkg << 2) + q;
      float y = acc[ct][q] + bb + pbuf[row] * wl;   // parity column (k=128), exact f32
      y = fmaxf(y, 0.0f);
      unsigned short h = f2bf(y);
      *(unsigned short*)((char*)xhi + swzb(row, col << 1)) = h;
      *(unsigned short*)((char*)xlo + swzb(row, col << 1)) = f2bf(y - bf2f(h));
    }
  }
  __syncthreads();

  // ---- layer 2 ----
  #pragma unroll
  for (int ct = 0; ct < 8; ++ct) acc[ct] = (f32x4){0.f, 0.f, 0.f, 0.f};
  gemm64(acc, (char*)xhi, (char*)xlo, (char*)wb, wrow + lrow, lrow, lkg);
  __syncthreads();

  stage_w((const uint4*)wsbb, wb, tid);  // weights for layer 3
  #pragma unroll
  for (int ct = 0; ct < 8; ++ct) {
    int col = ct * 16 + lrow;
    float bb = b2s[col];
    #pragma unroll
    for (int q = 0; q < 4; ++q) {
      int row = wrow + (lkg << 2) + q;
      size_t g = ((rowbase + row) << 7) + col;
      float hn = hD[g] + ALPHA_F * (acc[ct][q] + bb);
      outD[g] = hn;
      unsigned short h = f2bf(hn);
      *(unsigned short*)((char*)xhi + swzb(row, col << 1)) = h;
      *(unsigned short*)((char*)xlo + swzb(row, col << 1)) = f2bf(hn - bf2f(h));
    }
  }
  __syncthreads();

  // ---- layer 3 (hD_sb, [d][b][128] layout) ----
  #pragma unroll
  for (int ct = 0; ct < 8; ++ct) acc[ct] = (f32x4){0.f, 0.f, 0.f, 0.f};
  gemm64(acc, (char*)xhi, (char*)xlo, (char*)wb, wrow + lrow, lrow, lkg);
  #pragma unroll
  for (int ct = 0; ct < 8; ++ct) {
    int col = ct * 16 + lrow;
    #pragma unroll
    for (int q = 0; q < 4; ++q) {
      int row = wrow + (lkg << 2) + q;
      size_t gr = rowbase + row;                 // global row in [0, 4*N_D)
      size_t d_ = gr & (N_D - 1), b_ = gr >> 15;
      hD_sb[(d_ << 9) + (b_ << 7) + col] = acc[ct][q];
    }
  }
}

// ---------------- hE_new = hE + a * (sum gathered hD_sb blocks)/count ----------------
// one wave per e-node, covering all 4 batches (hD_sb is [d][4][128] = 2KB per d)
__global__ void agg_kernel(const float* __restrict__ hE, const float* __restrict__ sb,
                           const int* __restrict__ off_e, const int* __restrict__ list_e,
                           float* __restrict__ outE) {
  int e = (blockIdx.x * blockDim.x + threadIdx.x) >> 6;
  int lane = threadIdx.x & 63;
  if (e >= N_E) return;
  int s = off_e[e], t = off_e[e + 1];
  int deg = t - s;
  int myidx = (lane < deg) ? list_e[s + lane] : 0;
  f32x4 a0 = {0.f, 0.f, 0.f, 0.f}, a1 = {0.f, 0.f, 0.f, 0.f};
  int dlim = deg < 64 ? deg : 64;
  if (dlim > 0) {
    int d = __shfl(myidx, 0, 64);
    const float4* p = (const float4*)(sb + ((size_t)d << 9));
    float4 v0 = p[lane], v1 = p[lane + 64];
    for (int i = 1; i < dlim; ++i) {
      int dn = __shfl(myidx, i, 64);
      const float4* pn = (const float4*)(sb + ((size_t)dn << 9));
      float4 n0 = pn[lane], n1 = pn[lane + 64];   // prefetch before consuming v
      a0[0] += v0.x; a0[1] += v0.y; a0[2] += v0.z; a0[3] += v0.w;
      a1[0] += v1.x; a1[1] += v1.y; a1[2] += v1.z; a1[3] += v1.w;
      v0 = n0; v1 = n1;
    }
    a0[0] += v0.x; a0[1] += v0.y; a0[2] += v0.z; a0[3] += v0.w;
    a1[0] += v1.x; a1[1] += v1.y; a1[2] += v1.z; a1[3] += v1.w;
  }
  for (int i = 64; i < deg; ++i) {   // statistically never (deg ~ Poisson(4))
    int d = list_e[s + i];
    const float4* p = (const float4*)(sb + ((size_t)d << 9));
    float4 v0 = p[lane], v1 = p[lane + 64];
    a0[0] += v0.x; a0[1] += v0.y; a0[2] += v0.z; a0[3] += v0.w;
    a1[0] += v1.x; a1[1] += v1.y; a1[2] += v1.z; a1[3] += v1.w;
  }
  float sc = ALPHA_F / (float)(deg > 0 ? deg : 1);
  int b0 = lane >> 5, c4 = (lane & 31) << 2;
  size_t o0 = (((size_t)b0 * N_E + e) << 7) + c4;
  size_t o1 = ((((size_t)b0 + 2) * N_E + e) << 7) + c4;
  float4 h0 = *(const float4*)(hE + o0);
  float4 h1 = *(const float4*)(hE + o1);
  float4 r0, r1;
  r0.x = h0.x + sc * a0[0]; r0.y = h0.y + sc * a0[1];
  r0.z = h0.z + sc * a0[2]; r0.w = h0.w + sc * a0[3];
  r1.x = h1.x + sc * a1[0]; r1.y = h1.y + sc * a1[1];
  r1.z = h1.z + sc * a1[2]; r1.w = h1.w + sc * a1[3];
  *(float4*)(outE + o0) = r0;
  *(float4*)(outE + o1) = r1;
}

// ---------------- launch ----------------

extern "C" void kernel_launch(void* const* d_in, const int* in_sizes, int n_in,
                              void* d_out, int out_size, void* d_ws, size_t ws_size,
                              hipStream_t stream) {
  const float* hD    = (const float*)d_in[0];
  const float* hE    = (const float*)d_in[1];
  const int*   e2d   = (const int*)d_in[2];
  const int*   d2e   = (const int*)d_in[3];
  const float* w_llr = (const float*)d_in[4];
  const float* w1    = (const float*)d_in[5];
  const float* b1    = (const float*)d_in[6];
  const float* w2    = (const float*)d_in[7];
  const float* b2    = (const float*)d_in[8];
  const float* w_sb  = (const float*)d_in[9];

  float* outD = (float*)d_out;
  float* outE = outD + (size_t)NB * N_D * H;

  float* pt     = (float*)d_ws;
  float* parity = pt + (size_t)NB * N_E;
  float* hD_sb  = parity + (size_t)NB * N_D;
  int* cnt_d  = (int*)(hD_sb + (size_t)NB * N_D * H);
  int* off_d  = cnt_d + N_D;
  int* cur_d  = off_d + N_D + 1;
  int* cnt_e  = cur_d + N_D;
  int* off_e  = cnt_e + N_E;
  int* cur_e  = off_e + N_E + 1;
  int* list_d = cur_e + N_E;
  int* list_e = list_d + NEDGE;
  uintptr_t wp = (uintptr_t)(list_e + NEDGE);
  wp = (wp + 15) & ~(uintptr_t)15;
  unsigned short* w1b  = (unsigned short*)wp;            // 128*128 bf16
  unsigned short* w2b  = w1b + 128 * 128;
  unsigned short* wsbb = w2b + 128 * 128;
  float* w1last = (float*)(wsbb + 128 * 128);            // 128 f32

  hipMemsetAsync(cnt_d, 0, N_D * sizeof(int), stream);
  hipMemsetAsync(cnt_e, 0, N_E * sizeof(int), stream);

  count_kernel<<<NEDGE / 256, 256, 0, stream>>>(e2d, d2e, cnt_d, cnt_e, NEDGE);
  scan_kernel<32><<<1, 1024, 0, stream>>>(cnt_d, off_d, cur_d, N_D);
  scan_kernel<64><<<1, 1024, 0, stream>>>(cnt_e, off_e, cur_e, N_E);
  fill_kernel<<<NEDGE / 256, 256, 0, stream>>>(e2d, d2e, cur_d, cur_e, list_d, list_e, NEDGE);

  wsplit_kernel<<<64, 256, 0, stream>>>(w1, w2, w_sb, w1b, w1last, w2b, wsbb);

  pt_kernel<<<(NB * N_E) / 4, 256, 0, stream>>>(hE, w_llr, pt, NB * N_E);
  parity_kernel<<<(NB * N_D) / 256, 256, 0, stream>>>(pt, off_d, list_d, parity, NB * N_D);

  size_t fused_lds = (size_t)(64 * 128 * 2 * 2 + 128 * 128 * 2 + (64 + 128 + 128 + 128) * 4);
  hipFuncSetAttribute((const void*)fused_kernel, hipFuncAttributeMaxDynamicSharedMemorySize,
                      (int)fused_lds);
  fused_kernel<<<(NB * N_D) / 64, 256, fused_lds, stream>>>(
      hD, parity, w1b, w1last, b1, w2b, b2, wsbb, outD, hD_sb);

  agg_kernel<<<N_E / 4, 256, 0, stream>>>(hE, hD_sb, off_e, list_e, outE);
}

// Round 6
// 300.519 us; speedup vs baseline: 3.1404x; 1.1331x over previous
//
#include <hip/hip_runtime.h>
#include <cstdint>

#define ALPHA_F 0.1f
static const int NB    = 4;
static const int N_D   = 32768;   // 2^15
static const int N_E   = 65536;   // 2^16
static const int NEDGE = 262144;
static const int H     = 128;

typedef __attribute__((ext_vector_type(8))) short short8;
typedef __attribute__((ext_vector_type(4))) float f32x4;

__device__ __forceinline__ unsigned short f2bf(float x) {
  union { float f; unsigned u; } v; v.f = x;
  unsigned u = v.u + (0x7FFFu + ((v.u >> 16) & 1u));   // RNE
  return (unsigned short)(u >> 16);
}
__device__ __forceinline__ float bf2f(unsigned short h) {
  union { unsigned u; float f; } v; v.u = ((unsigned)h) << 16;
  return v.f;
}
// byte offset of element k-byte `kbyte` in row `row` of a [R][128]-bf16 LDS tile,
// XOR-swizzled so 16 lanes reading the same k of rows 0..15 spread across 8 bank-quads
__device__ __forceinline__ int swzb(int row, int kbyte) {
  return (row * 256 + kbyte) ^ ((row & 7) << 4);
}

// ---------------- CSR build ----------------

__global__ void count_kernel(const int* __restrict__ e2d, const int* __restrict__ d2e,
                             int* __restrict__ cnt_d, int* __restrict__ cnt_e, int E) {
  int k = blockIdx.x * blockDim.x + threadIdx.x;
  if (k >= E) return;
  atomicAdd(&cnt_d[e2d[E + k]], 1);
  atomicAdd(&cnt_e[d2e[E + k]], 1);
}

// exclusive scan of n ints, 1 block of 1024, CHUNK contiguous elems per thread
template <int CHUNK>
__global__ void scan_kernel(const int* __restrict__ cnt, int* __restrict__ off,
                            int* __restrict__ cursor, int n) {
  __shared__ int partial[1024];
  int tid = threadIdx.x;
  int base = tid * CHUNK;
  int4 vals[CHUNK / 4];
  const int4* c4 = (const int4*)(cnt + base);
  int sum = 0;
  #pragma unroll
  for (int i = 0; i < CHUNK / 4; ++i) {
    vals[i] = c4[i];
    sum += vals[i].x + vals[i].y + vals[i].z + vals[i].w;
  }
  partial[tid] = sum;
  __syncthreads();
  for (int s = 1; s < 1024; s <<= 1) {
    int v = (tid >= s) ? partial[tid - s] : 0;
    __syncthreads();
    partial[tid] += v;
    __syncthreads();
  }
  int run = partial[tid] - sum;
  int4* o4 = (int4*)(off + base);
  int4* cu4 = (int4*)(cursor + base);
  #pragma unroll
  for (int i = 0; i < CHUNK / 4; ++i) {
    int4 o;
    o.x = run; run += vals[i].x;
    o.y = run; run += vals[i].y;
    o.z = run; run += vals[i].z;
    o.w = run; run += vals[i].w;
    o4[i] = o;
    cu4[i] = o;
  }
  if (tid == 1023) off[n] = run;
}

__global__ void fill_kernel(const int* __restrict__ e2d, const int* __restrict__ d2e,
                            int* __restrict__ cur_d, int* __restrict__ cur_e,
                            int* __restrict__ list_d, int* __restrict__ list_e, int E) {
  int k = blockIdx.x * blockDim.x + threadIdx.x;
  if (k >= E) return;
  int es = e2d[k], dd = e2d[E + k];
  int p1 = atomicAdd(&cur_d[dd], 1);
  list_d[p1] = es;
  int ds = d2e[k], ed = d2e[E + k];
  int p2 = atomicAdd(&cur_e[ed], 1);
  list_e[p2] = ds;
}

// ---------------- pt = clip(-tanh(llr/2)) ----------------
__global__ void pt_kernel(const float* __restrict__ hE, const float* __restrict__ w_llr,
                          float* __restrict__ pt, int nrows) {
  int wave = (blockIdx.x * blockDim.x + threadIdx.x) >> 6;
  int lane = threadIdx.x & 63;
  if (wave >= nrows) return;
  float2 v = reinterpret_cast<const float2*>(hE)[(size_t)wave * 64 + lane];
  float2 w = reinterpret_cast<const float2*>(w_llr)[lane];
  float s = v.x * w.x + v.y * w.y;
  #pragma unroll
  for (int off = 32; off > 0; off >>= 1) s += __shfl_down(s, off, 64);
  if (lane == 0) {
    float p = -tanhf(0.5f * s);
    pt[wave] = fminf(fmaxf(p, -0.999f), 0.999f);
  }
}

// ---------------- parity per (b,d) ----------------
__global__ void parity_kernel(const float* __restrict__ pt, const int* __restrict__ off_d,
                              const int* __restrict__ list_d, float* __restrict__ parity,
                              int total) {
  int idx = blockIdx.x * blockDim.x + threadIdx.x;
  if (idx >= total) return;
  int d = idx & (N_D - 1);
  int b = idx >> 15;
  const float* ptb = pt + (size_t)b * N_E;
  int s = off_d[d], t = off_d[d + 1];
  float lg = 0.0f;
  int neg = 0;
  for (int i = s; i < t; ++i) {
    float p = ptb[list_d[i]];
    lg += logf(fmaxf(fabsf(p), 1e-8f));
    neg ^= (p < 0.0f) ? 1 : 0;
  }
  float par = expf(fminf(lg, 20.0f));
  parity[idx] = neg ? -par : par;
}

// ---------------- weight pre-pack to bf16 ----------------
__global__ void wsplit_kernel(const float* __restrict__ w1, const float* __restrict__ w2,
                              const float* __restrict__ wsb,
                              unsigned short* __restrict__ w1b, float* __restrict__ w1last,
                              unsigned short* __restrict__ w2b, unsigned short* __restrict__ wsbb) {
  int idx = blockIdx.x * blockDim.x + threadIdx.x;
  if (idx >= 128 * 128) return;
  int n = idx >> 7, k = idx & 127;
  w1b[idx]  = f2bf(w1[n * 129 + k]);
  w2b[idx]  = f2bf(w2[idx]);
  wsbb[idx] = f2bf(wsb[idx]);
  if (k == 0) w1last[n] = w1[n * 129 + 128];
}

// stage a 128x128 bf16 weight matrix (row-major, 16B chunks) into swizzled LDS
__device__ __forceinline__ void stage_w(const uint4* __restrict__ src,
                                        unsigned short* wb, int tid) {
  #pragma unroll
  for (int r = 0; r < 8; ++r) {
    int i = tid + r * 256;            // 2048 chunks of 16B
    int n = i >> 4, kc = (i & 15) << 4;
    *(uint4*)((char*)wb + ((n * 256 + kc) ^ ((n & 7) << 4))) = src[i];
  }
}

// one layer: acc[ct] += sum_k (xhi+xlo)[arow][k] * w[ct*16+lrow][k], K=128
__device__ __forceinline__ void gemm64(f32x4* acc, const char* xhiB, const char* xloB,
                                       const char* wbB, int arow, int lrow, int lkg) {
  int kb0 = lkg << 4;
  #pragma unroll
  for (int ks = 0; ks < 4; ++ks) {
    int kb = (ks << 6) + kb0;
    short8 ahi = *(const short8*)(xhiB + swzb(arow, kb));
    short8 alo = *(const short8*)(xloB + swzb(arow, kb));
    #pragma unroll
    for (int ct = 0; ct < 8; ++ct) {
      short8 b = *(const short8*)(wbB + swzb(ct * 16 + lrow, kb));
      acc[ct] = __builtin_amdgcn_mfma_f32_16x16x32_bf16(ahi, b, acc[ct], 0, 0, 0);
      acc[ct] = __builtin_amdgcn_mfma_f32_16x16x32_bf16(alo, b, acc[ct], 0, 0, 0);
    }
  }
}

// ---------------- fused: hD_new = hD + a*MLP([hD,par]); hD_sb = hD_new @ w_sb^T ----------------
// hD_sb written as bf16 in [d][b][128] layout for the aggregation gather.
// 256 threads = 4 waves; each wave owns 16 rows x 128 cols; block tile = 64 rows.
__global__ void __launch_bounds__(256) fused_kernel(
    const float* __restrict__ hD, const float* __restrict__ parity,
    const unsigned short* __restrict__ w1b, const float* __restrict__ w1last,
    const float* __restrict__ b1, const unsigned short* __restrict__ w2b,
    const float* __restrict__ b2, const unsigned short* __restrict__ wsbb,
    float* __restrict__ outD, unsigned short* __restrict__ hD_sb) {
  extern __shared__ char lds[];
  unsigned short* xhi = (unsigned short*)lds;          // [64][128] bf16, swizzled
  unsigned short* xlo = xhi + 64 * 128;
  unsigned short* wb  = xlo + 64 * 128;                // [128][128] bf16, swizzled
  float* pbuf  = (float*)(wb + 128 * 128);             // [64]
  float* wlast = pbuf + 64;                            // [128]
  float* b1s   = wlast + 128;
  float* b2s   = b1s + 128;

  int tid  = threadIdx.x;
  int lane = tid & 63, wv = tid >> 6;
  int lrow = lane & 15, lkg = lane >> 4;
  int wrow = wv << 4;
  size_t rowbase = (size_t)blockIdx.x << 6;

  // stage x = hD tile (split hi/lo bf16)
  const float4* hD4 = (const float4*)(hD + (rowbase << 7));
  #pragma unroll
  for (int it = 0; it < 8; ++it) {
    int i = tid + it * 256;                    // 2048 float4 = 64 rows x 32
    float4 v = hD4[i];
    int row = i >> 5, kb = (i & 31) << 3;      // byte offset within row (bf16*2 per elem)
    unsigned short h0 = f2bf(v.x), h1 = f2bf(v.y), h2 = f2bf(v.z), h3 = f2bf(v.w);
    unsigned short l0 = f2bf(v.x - bf2f(h0)), l1 = f2bf(v.y - bf2f(h1));
    unsigned short l2 = f2bf(v.z - bf2f(h2)), l3 = f2bf(v.w - bf2f(h3));
    *(unsigned*)((char*)xhi + swzb(row, kb))     = h0 | ((unsigned)h1 << 16);
    *(unsigned*)((char*)xhi + swzb(row, kb + 4)) = h2 | ((unsigned)h3 << 16);
    *(unsigned*)((char*)xlo + swzb(row, kb))     = l0 | ((unsigned)l1 << 16);
    *(unsigned*)((char*)xlo + swzb(row, kb + 4)) = l2 | ((unsigned)l3 << 16);
  }
  stage_w((const uint4*)w1b, wb, tid);
  if (tid < 64) pbuf[tid] = parity[rowbase + tid];
  if (tid < 128) { wlast[tid] = w1last[tid]; b1s[tid] = b1[tid]; b2s[tid] = b2[tid]; }
  __syncthreads();

  // ---- layer 1 ----
  f32x4 acc[8];
  #pragma unroll
  for (int ct = 0; ct < 8; ++ct) acc[ct] = (f32x4){0.f, 0.f, 0.f, 0.f};
  gemm64(acc, (char*)xhi, (char*)xlo, (char*)wb, wrow + lrow, lrow, lkg);
  __syncthreads();

  stage_w((const uint4*)w2b, wb, tid);   // overwrite weights for layer 2
  #pragma unroll
  for (int ct = 0; ct < 8; ++ct) {
    int col = ct * 16 + lrow;
    float wl = wlast[col], bb = b1s[col];
    #pragma unroll
    for (int q = 0; q < 4; ++q) {
      int row = wrow + (lkg << 2) + q;
      float y = acc[ct][q] + bb + pbuf[row] * wl;   // parity column (k=128), exact f32
      y = fmaxf(y, 0.0f);
      unsigned short h = f2bf(y);
      *(unsigned short*)((char*)xhi + swzb(row, col << 1)) = h;
      *(unsigned short*)((char*)xlo + swzb(row, col << 1)) = f2bf(y - bf2f(h));
    }
  }
  __syncthreads();

  // ---- layer 2 ----
  #pragma unroll
  for (int ct = 0; ct < 8; ++ct) acc[ct] = (f32x4){0.f, 0.f, 0.f, 0.f};
  gemm64(acc, (char*)xhi, (char*)xlo, (char*)wb, wrow + lrow, lrow, lkg);
  __syncthreads();

  stage_w((const uint4*)wsbb, wb, tid);  // weights for layer 3
  #pragma unroll
  for (int ct = 0; ct < 8; ++ct) {
    int col = ct * 16 + lrow;
    float bb = b2s[col];
    #pragma unroll
    for (int q = 0; q < 4; ++q) {
      int row = wrow + (lkg << 2) + q;
      size_t g = ((rowbase + row) << 7) + col;
      float hn = hD[g] + ALPHA_F * (acc[ct][q] + bb);
      __builtin_nontemporal_store(hn, &outD[g]);   // outD never re-read on device
      unsigned short h = f2bf(hn);
      *(unsigned short*)((char*)xhi + swzb(row, col << 1)) = h;
      *(unsigned short*)((char*)xlo + swzb(row, col << 1)) = f2bf(hn - bf2f(h));
    }
  }
  __syncthreads();

  // ---- layer 3 (hD_sb, bf16 [d][4][128] layout) ----
  #pragma unroll
  for (int ct = 0; ct < 8; ++ct) acc[ct] = (f32x4){0.f, 0.f, 0.f, 0.f};
  gemm64(acc, (char*)xhi, (char*)xlo, (char*)wb, wrow + lrow, lrow, lkg);
  #pragma unroll
  for (int ct = 0; ct < 8; ++ct) {
    int col = ct * 16 + lrow;
    #pragma unroll
    for (int q = 0; q < 4; ++q) {
      int row = wrow + (lkg << 2) + q;
      size_t gr = rowbase + row;                 // global row in [0, 4*N_D)
      size_t d_ = gr & (N_D - 1), b_ = gr >> 15;
      hD_sb[(d_ << 9) + (b_ << 7) + col] = f2bf(acc[ct][q]);
    }
  }
}

// ---------------- hE_new = hE + a * (sum gathered hD_sb blocks)/count ----------------
// one wave per e-node, all 4 batches (hD_sb is bf16 [d][4][128] = 1KB per d)
__device__ __forceinline__ void acc_pair(float& lo, float& hi, unsigned u) {
  union { unsigned u; float f; } a, b;
  a.u = u << 16; b.u = u & 0xFFFF0000u;
  lo += a.f; hi += b.f;
}
__device__ __forceinline__ void acc8(float* a, uint4 v) {
  acc_pair(a[0], a[1], v.x);
  acc_pair(a[2], a[3], v.y);
  acc_pair(a[4], a[5], v.z);
  acc_pair(a[6], a[7], v.w);
}

__global__ void agg_kernel(const float* __restrict__ hE, const unsigned short* __restrict__ sb,
                           const int* __restrict__ off_e, const int* __restrict__ list_e,
                           float* __restrict__ outE) {
  int e = (blockIdx.x * blockDim.x + threadIdx.x) >> 6;
  int lane = threadIdx.x & 63;
  if (e >= N_E) return;
  int s = off_e[e], t = off_e[e + 1];
  int deg = t - s;
  int myidx = (lane < deg) ? list_e[s + lane] : 0;
  float a[8];
  #pragma unroll
  for (int i = 0; i < 8; ++i) a[i] = 0.f;
  int dlim = deg < 64 ? deg : 64;
  if (dlim > 0) {
    int d = __shfl(myidx, 0, 64);
    uint4 v = *(const uint4*)(sb + ((size_t)d << 9) + lane * 8);
    for (int i = 1; i < dlim; ++i) {
      int dn = __shfl(myidx, i, 64);
      uint4 n = *(const uint4*)(sb + ((size_t)dn << 9) + lane * 8);  // prefetch
      acc8(a, v);
      v = n;
    }
    acc8(a, v);
  }
  for (int i = 64; i < deg; ++i) {   // statistically never (deg ~ Poisson(4))
    int d = list_e[s + i];
    acc8(a, *(const uint4*)(sb + ((size_t)d << 9) + lane * 8));
  }
  float sc = ALPHA_F / (float)(deg > 0 ? deg : 1);
  int b0 = lane >> 4, c8 = (lane & 15) << 3;          // batch, col-block of 8
  size_t o0 = (((size_t)b0 * N_E + e) << 7) + c8;
  f32x4 h0 = __builtin_nontemporal_load((const f32x4*)(hE + o0));
  f32x4 h1 = __builtin_nontemporal_load((const f32x4*)(hE + o0 + 4));
  f32x4 r0, r1;
  #pragma unroll
  for (int i = 0; i < 4; ++i) { r0[i] = h0[i] + sc * a[i]; r1[i] = h1[i] + sc * a[i + 4]; }
  __builtin_nontemporal_store(r0, (f32x4*)(outE + o0));
  __builtin_nontemporal_store(r1, (f32x4*)(outE + o0 + 4));
}

// ---------------- launch ----------------

extern "C" void kernel_launch(void* const* d_in, const int* in_sizes, int n_in,
                              void* d_out, int out_size, void* d_ws, size_t ws_size,
                              hipStream_t stream) {
  const float* hD    = (const float*)d_in[0];
  const float* hE    = (const float*)d_in[1];
  const int*   e2d   = (const int*)d_in[2];
  const int*   d2e   = (const int*)d_in[3];
  const float* w_llr = (const float*)d_in[4];
  const float* w1    = (const float*)d_in[5];
  const float* b1    = (const float*)d_in[6];
  const float* w2    = (const float*)d_in[7];
  const float* b2    = (const float*)d_in[8];
  const float* w_sb  = (const float*)d_in[9];

  float* outD = (float*)d_out;
  float* outE = outD + (size_t)NB * N_D * H;

  float* pt     = (float*)d_ws;
  float* parity = pt + (size_t)NB * N_E;
  unsigned short* hD_sb = (unsigned short*)(parity + (size_t)NB * N_D);   // bf16, [N_D][4][128]
  int* cnt_d  = (int*)((float*)hD_sb + (size_t)NB * N_D * H);   // region kept f32-sized
  int* off_d  = cnt_d + N_D;
  int* cur_d  = off_d + N_D + 1;
  int* cnt_e  = cur_d + N_D;
  int* off_e  = cnt_e + N_E;
  int* cur_e  = off_e + N_E + 1;
  int* list_d = cur_e + N_E;
  int* list_e = list_d + NEDGE;
  uintptr_t wp = (uintptr_t)(list_e + NEDGE);
  wp = (wp + 15) & ~(uintptr_t)15;
  unsigned short* w1b  = (unsigned short*)wp;            // 128*128 bf16
  unsigned short* w2b  = w1b + 128 * 128;
  unsigned short* wsbb = w2b + 128 * 128;
  float* w1last = (float*)(wsbb + 128 * 128);            // 128 f32

  hipMemsetAsync(cnt_d, 0, N_D * sizeof(int), stream);
  hipMemsetAsync(cnt_e, 0, N_E * sizeof(int), stream);

  count_kernel<<<NEDGE / 256, 256, 0, stream>>>(e2d, d2e, cnt_d, cnt_e, NEDGE);
  scan_kernel<32><<<1, 1024, 0, stream>>>(cnt_d, off_d, cur_d, N_D);
  scan_kernel<64><<<1, 1024, 0, stream>>>(cnt_e, off_e, cur_e, N_E);
  fill_kernel<<<NEDGE / 256, 256, 0, stream>>>(e2d, d2e, cur_d, cur_e, list_d, list_e, NEDGE);

  wsplit_kernel<<<64, 256, 0, stream>>>(w1, w2, w_sb, w1b, w1last, w2b, wsbb);

  pt_kernel<<<(NB * N_E) / 4, 256, 0, stream>>>(hE, w_llr, pt, NB * N_E);
  parity_kernel<<<(NB * N_D) / 256, 256, 0, stream>>>(pt, off_d, list_d, parity, NB * N_D);

  size_t fused_lds = (size_t)(64 * 128 * 2 * 2 + 128 * 128 * 2 + (64 + 128 + 128 + 128) * 4);
  hipFuncSetAttribute((const void*)fused_kernel, hipFuncAttributeMaxDynamicSharedMemorySize,
                      (int)fused_lds);
  fused_kernel<<<(NB * N_D) / 64, 256, fused_lds, stream>>>(
      hD, parity, w1b, w1last, b1, w2b, b2, wsbb, outD, hD_sb);

  agg_kernel<<<N_E / 4, 256, 0, stream>>>(hE, hD_sb, off_e, list_e, outE);
}